// Round 1
// baseline (355.063 us; speedup 1.0000x reference)
//
#include <hip/hip_runtime.h>

constexpr int BATCH   = 16384;
constexpr int NCLS    = 1000;   // classes
constexpr int PROTO   = 4;      // prototypes per class
constexpr int THREADS = 256;    // 4 waves

// One block per row. Each class = contiguous float4 -> coalesced 16B/lane loads.
__global__ __launch_bounds__(THREADS)
void mpl_row_kernel(const float* __restrict__ dist,
                    const int*   __restrict__ labels,
                    float*       __restrict__ terms) {
    const int row = blockIdx.x;
    const float4* __restrict__ rp =
        reinterpret_cast<const float4*>(dist + (size_t)row * (NCLS * PROTO));
    const int lab = labels[row];
    const int t   = threadIdx.x;

    float sum   = 0.0f;   // sum of d over this thread's classes
    float incls = 0.0f;
    bool  have  = false;

    for (int c = t; c < NCLS; c += THREADS) {
        float4 v = rp[c];
        // soft-min over 4 prototypes: d = -logsumexp(-x) = m - log(sum exp(m - x))
        float m = fminf(fminf(v.x, v.y), fminf(v.z, v.w));
        float s = expf(m - v.x) + expf(m - v.y) + expf(m - v.z) + expf(m - v.w);
        float d = m - logf(s);
        sum += d;
        if (c == lab) { incls = d; have = true; }
    }

    // intra-wave butterfly (64 lanes) then cross-wave via LDS
    #pragma unroll
    for (int off = 32; off; off >>= 1) sum += __shfl_down(sum, off, 64);

    __shared__ float s_wave[THREADS / 64];
    __shared__ float s_in;
    const int lane = t & 63, wid = t >> 6;
    if (lane == 0) s_wave[wid] = sum;
    if (have)      s_in = incls;          // exactly one thread owns the label class
    __syncthreads();

    if (t == 0) {
        float total = s_wave[0] + s_wave[1] + s_wave[2] + s_wave[3];
        float ic    = s_in;
        float om    = (total - ic) * (1.0f / (NCLS - 1));
        terms[row]  = (ic * ic) / (om * om);
    }
}

// Single-block reduction of 16384 per-row terms -> mean
__global__ __launch_bounds__(THREADS)
void mpl_reduce_kernel(const float* __restrict__ terms,
                       float*       __restrict__ out) {
    const int t = threadIdx.x;
    const float4* __restrict__ tp = reinterpret_cast<const float4*>(terms);
    float sum = 0.0f;
    for (int i = t; i < BATCH / 4; i += THREADS) {
        float4 v = tp[i];
        sum += (v.x + v.y) + (v.z + v.w);
    }
    #pragma unroll
    for (int off = 32; off; off >>= 1) sum += __shfl_down(sum, off, 64);

    __shared__ float s_wave[THREADS / 64];
    const int lane = t & 63, wid = t >> 6;
    if (lane == 0) s_wave[wid] = sum;
    __syncthreads();
    if (t == 0) {
        out[0] = (s_wave[0] + s_wave[1] + s_wave[2] + s_wave[3]) * (1.0f / BATCH);
    }
}

extern "C" void kernel_launch(void* const* d_in, const int* in_sizes, int n_in,
                              void* d_out, int out_size, void* d_ws, size_t ws_size,
                              hipStream_t stream) {
    const float* dist   = (const float*)d_in[0];
    const int*   labels = (const int*)d_in[1];
    float*       terms  = (float*)d_ws;   // 16384 floats of scratch
    float*       out    = (float*)d_out;

    mpl_row_kernel<<<BATCH, THREADS, 0, stream>>>(dist, labels, terms);
    mpl_reduce_kernel<<<1, THREADS, 0, stream>>>(terms, out);
}